// Round 4
// baseline (3657.467 us; speedup 1.0000x reference)
//
#include <hip/hip_runtime.h>
#include <stdint.h>

#define D_MODEL   1024
#define D_STATE   64
#define D_INNER   2048
#define NHEADS    32
#define CONV_DIM  2176
#define D_IN_PROJ 4256
#define NPAD1     4352   // 34*128, padded N for in_proj GEMM
#define LSEQ      4096
#define BL        8192   // B*L
#define CH        1024   // conv/scan time-chunk length
#define EPS       1e-5f

typedef __attribute__((ext_vector_type(8))) __bf16 bf16x8;
typedef __attribute__((ext_vector_type(4))) float f32x4;

__device__ __forceinline__ unsigned short f2bf(float f) {
  union { float f; unsigned u; } v; v.f = f;
  unsigned r = v.u + 0x7fffu + ((v.u >> 16) & 1u);   // RNE
  return (unsigned short)(r >> 16);
}
__device__ __forceinline__ float bf2f(unsigned short h) {
  union { unsigned u; float f; } v; v.u = (unsigned)h << 16;
  return v.f;
}
__device__ __forceinline__ void split_bf(float x, unsigned short& hi, unsigned short& lo) {
  hi = f2bf(x);
  lo = f2bf(x - bf2f(hi));
}
__device__ __forceinline__ void load_lds16(const void* g, void* l) {
  __builtin_amdgcn_global_load_lds((const __attribute__((address_space(1))) void*)g,
                                   (__attribute__((address_space(3))) void*)l, 16, 0, 0);
}

// ---------------- weight casts: fp32 -> bf16 hi/lo pairs ----------------
__global__ __launch_bounds__(256) void cvt_w1_kernel(const float* __restrict__ w,
                                                     unsigned short* __restrict__ hi,
                                                     unsigned short* __restrict__ lo) {
  size_t idx = (size_t)blockIdx.x * 256 + threadIdx.x;   // over 2*4352*1024
  int k = idx & 1023;
  size_t nr = idx >> 10;
  int layer = (int)(nr / NPAD1);
  int n = (int)(nr % NPAD1);
  float v = (n < D_IN_PROJ) ? w[((size_t)layer * D_IN_PROJ + n) * 1024 + k] : 0.f;
  unsigned short h, l; split_bf(v, h, l);
  hi[idx] = h; lo[idx] = l;
}
__global__ __launch_bounds__(256) void cvt_w2_kernel(const float* __restrict__ w,
                                                     unsigned short* __restrict__ hi,
                                                     unsigned short* __restrict__ lo) {
  size_t idx = (size_t)blockIdx.x * 256 + threadIdx.x;   // over 2*1024*2048
  unsigned short h, l; split_bf(w[idx], h, l);
  hi[idx] = h; lo[idx] = l;
}

// ---------------- layernorm (row of 1024), fp32 in -> bf16 hi/lo out ----------------
__global__ __launch_bounds__(256) void ln_kernel(const float* __restrict__ x,
                                                 const float* __restrict__ w,
                                                 const float* __restrict__ b,
                                                 unsigned short* __restrict__ ohi,
                                                 unsigned short* __restrict__ olo) {
  int row = blockIdx.x, tid = threadIdx.x;
  const float* xr = x + (size_t)row * D_MODEL;
  float4 v = *(const float4*)(xr + tid * 4);
  float s = v.x + v.y + v.z + v.w;
  float q = v.x * v.x + v.y * v.y + v.z * v.z + v.w * v.w;
  for (int off = 1; off < 64; off <<= 1) { s += __shfl_xor(s, off); q += __shfl_xor(q, off); }
  __shared__ float rs[4], rq[4];
  int wave = tid >> 6, lane = tid & 63;
  if (lane == 0) { rs[wave] = s; rq[wave] = q; }
  __syncthreads();
  s = rs[0] + rs[1] + rs[2] + rs[3];
  q = rq[0] + rq[1] + rq[2] + rq[3];
  float mean = s * (1.f / D_MODEL);
  float var = q * (1.f / D_MODEL) - mean * mean;
  float rstd = rsqrtf(var + EPS);
  int c = tid * 4;
  ushort4 hv, lv;
  float y0 = (v.x - mean) * rstd * w[c + 0] + b[c + 0];
  float y1 = (v.y - mean) * rstd * w[c + 1] + b[c + 1];
  float y2 = (v.z - mean) * rstd * w[c + 2] + b[c + 2];
  float y3 = (v.w - mean) * rstd * w[c + 3] + b[c + 3];
  split_bf(y0, hv.x, lv.x); split_bf(y1, hv.y, lv.y);
  split_bf(y2, hv.z, lv.z); split_bf(y3, hv.w, lv.w);
  *(ushort4*)(ohi + (size_t)row * D_MODEL + c) = hv;
  *(ushort4*)(olo + (size_t)row * D_MODEL + c) = lv;
}

// ---------------- split-bf16 GEMM (bf16x3): C = (Ahi+Alo)(Bhi+Blo)^T ----------------
// 128x128 tile, BK=32, 4 waves. MODE 0: in_proj epilogue (z bf16 / xpre fp32 / aux fp32).
// MODE 1: fp32 out + fp32 resid (out_proj).
template <int MODE>
__global__ __launch_bounds__(256) void gemm_split_kernel(
    const unsigned short* __restrict__ Ahi, const unsigned short* __restrict__ Alo, int lda,
    const unsigned short* __restrict__ Bhi, const unsigned short* __restrict__ Blo, int K,
    unsigned short* __restrict__ Zb, float* __restrict__ XPRE, float* __restrict__ AUX,
    float* __restrict__ Cf, const float* __restrict__ resid) {
  __shared__ unsigned short lAh[128 * 32], lAl[128 * 32];
  __shared__ unsigned short lBh[128 * 32], lBl[128 * 32];
  int tid = threadIdx.x;
  int wave = tid >> 6, lane = tid & 63;
  int bn = blockIdx.x, bm = blockIdx.y;
  const int rA = lane >> 2;
  const int cA = (lane & 3) * 8;     // LDS byte dest = wave-uniform + lane*16 (HW reqt)
  const int wm = (wave >> 1) * 64, wn = (wave & 1) * 64;
  const int fr = lane & 15;
  const int fk = (lane >> 4) * 8;
  size_t aoff = (size_t)(bm * 128) * lda;
  size_t boff = (size_t)(bn * 128) * K;
  f32x4 acc[4][4];
  f32x4 zero = {0.f, 0.f, 0.f, 0.f};
#pragma unroll
  for (int i = 0; i < 4; ++i)
#pragma unroll
    for (int j = 0; j < 4; ++j) acc[i][j] = zero;

  for (int k0 = 0; k0 < K; k0 += 32) {
#pragma unroll
    for (int c = 0; c < 2; ++c) {
      int row = (wave * 2 + c) * 16 + rA;
      size_t ga = aoff + (size_t)row * lda + k0 + cA;
      size_t gb = boff + (size_t)row * K + k0 + cA;
      load_lds16(Ahi + ga, &lAh[row * 32 + cA]);
      load_lds16(Alo + ga, &lAl[row * 32 + cA]);
      load_lds16(Bhi + gb, &lBh[row * 32 + cA]);
      load_lds16(Blo + gb, &lBl[row * 32 + cA]);
    }
    __syncthreads();
    bf16x8 ah[4], al[4], bh[4], bl[4];
#pragma unroll
    for (int i = 0; i < 4; ++i) {
      ah[i] = *(const bf16x8*)&lAh[(wm + i * 16 + fr) * 32 + fk];
      al[i] = *(const bf16x8*)&lAl[(wm + i * 16 + fr) * 32 + fk];
    }
#pragma unroll
    for (int j = 0; j < 4; ++j) {
      bh[j] = *(const bf16x8*)&lBh[(wn + j * 16 + fr) * 32 + fk];
      bl[j] = *(const bf16x8*)&lBl[(wn + j * 16 + fr) * 32 + fk];
    }
#pragma unroll
    for (int i = 0; i < 4; ++i)
#pragma unroll
      for (int j = 0; j < 4; ++j) {
        acc[i][j] = __builtin_amdgcn_mfma_f32_16x16x32_bf16(al[i], bh[j], acc[i][j], 0, 0, 0);
        acc[i][j] = __builtin_amdgcn_mfma_f32_16x16x32_bf16(ah[i], bl[j], acc[i][j], 0, 0, 0);
        acc[i][j] = __builtin_amdgcn_mfma_f32_16x16x32_bf16(ah[i], bh[j], acc[i][j], 0, 0, 0);
      }
    __syncthreads();
  }
  // epilogue: D layout col=lane&15, row=(lane>>4)*4+reg
  int r0 = (lane >> 4) * 4;
  int cc = lane & 15;
#pragma unroll
  for (int i = 0; i < 4; ++i) {
#pragma unroll
    for (int j = 0; j < 4; ++j) {
      int col = bn * 128 + wn + j * 16 + cc;
#pragma unroll
      for (int r = 0; r < 4; ++r) {
        size_t row = (size_t)(bm * 128 + wm + i * 16 + r0 + r);
        float v = acc[i][j][r];
        if constexpr (MODE == 0) {
          if (col < 2048)       Zb[row * 2048 + col] = f2bf(v);
          else if (col < 4096)  XPRE[row * 2048 + (col - 2048)] = v;
          else if (col < 4256)  AUX[row * 160 + (col - 4096)] = v;
        } else {
          size_t idx = row * 1024 + col;
          Cf[idx] = v + resid[idx];
        }
      }
    }
  }
}

// ---------------- dt = softplus(dt_raw + dt_bias), fp32 chain ----------------
__global__ __launch_bounds__(256) void dt_kernel(const float* __restrict__ aux,
                                                 const float* __restrict__ dtb,
                                                 float* __restrict__ dto) {
  int idx = blockIdx.x * 256 + threadIdx.x;   // < BL*32
  int l = idx >> 5, h = idx & 31;
  float v = aux[(size_t)l * 160 + 128 + h] + dtb[h];
  dto[idx] = (v > 20.f) ? v : log1pf(expf(v));
}

// ---------------- causal depthwise conv (width 4) + bias + silu, one time-chunk ----------------
__global__ __launch_bounds__(256) void conv_chunk_kernel(const float* __restrict__ xpre,
                                                         const float* __restrict__ aux,
                                                         const float* __restrict__ cw,
                                                         const float* __restrict__ cb,
                                                         int t0,
                                                         float* __restrict__ xhc,
                                                         float* __restrict__ Bo,
                                                         float* __restrict__ Co) {
  int lr = blockIdx.x;                      // 0..2*CH-1 chunk-local row
  int c = blockIdx.y * 256 + threadIdx.x;
  if (c >= CONV_DIM) return;
  int b = lr >> 10, tl = lr & (CH - 1);
  int t = t0 + tl;
  int l = b * LSEQ + t;                     // global row
  float acc = cb[c];
#pragma unroll
  for (int j = 0; j < 4; ++j) {
    int tt = t - 3 + j;
    if (tt >= 0) {
      size_t ll = (size_t)(b * LSEQ + tt);
      float xv = (c < 2048) ? xpre[ll * 2048 + c] : aux[ll * 160 + (c - 2048)];
      acc += xv * cw[c * 4 + j];
    }
  }
  acc = acc / (1.f + __expf(-acc));   // silu
  if (c < D_INNER)
    xhc[(size_t)lr * D_INNER + c] = acc;
  else if (c < D_INNER + D_STATE)
    Bo[(size_t)l * D_STATE + (c - D_INNER)] = acc;
  else
    Co[(size_t)l * D_STATE + (c - D_INNER - D_STATE)] = acc;
}

// ---------------- sequential SSM scan, one time-chunk, state carried in ws ----------------
// grid 256: (b, h, p-quarter). 256 thr: pl=tid>>4 (local p), n0=(tid&15)*4. 4 states/thread.
__global__ __launch_bounds__(256) void scan_chunk_kernel(const float* __restrict__ xhc,
                                                         const float* __restrict__ Bc,
                                                         const float* __restrict__ Cc,
                                                         const float* __restrict__ dtv,
                                                         const float* __restrict__ A_log,
                                                         const float* __restrict__ Dv,
                                                         int t0,
                                                         float* __restrict__ state,
                                                         float* __restrict__ y) {
  int bid = blockIdx.x;
  int b = bid >> 7, h = (bid >> 2) & 31, pq = bid & 3;
  int tid = threadIdx.x;
  int pl = tid >> 4;
  int n0 = (tid & 15) * 4;
  float A = -__expf(A_log[h]);       // A = -exp(A_log); __expf IS e^x
  float Dh = Dv[h];
  int p = pq * 16 + pl;
  size_t sidx = ((size_t)bid * 256 + tid) * 4;
  float s0, s1, s2, s3;
  if (t0 == 0) { s0 = s1 = s2 = s3 = 0.f; }
  else { s0 = state[sidx]; s1 = state[sidx + 1]; s2 = state[sidx + 2]; s3 = state[sidx + 3]; }
  __shared__ float sB[8][64], sC[8][64], sdt[8], sdA[8];
  __shared__ float sx[8][16];
  size_t gbase = (size_t)b * LSEQ + t0;
  size_t cbase = (size_t)b * CH;
  for (int tt = 0; tt < CH; tt += 8) {
    size_t gr = gbase + tt;
    size_t cr = cbase + tt;
#pragma unroll
    for (int qq = 0; qq < 2; ++qq) {
      int ii = qq * 256 + tid;
      int j = ii >> 6, n = ii & 63;
      sB[j][n] = Bc[(gr + j) * 64 + n];
      sC[j][n] = Cc[(gr + j) * 64 + n];
    }
    if (tid < 128) {
      int j = tid >> 4, pp = tid & 15;
      sx[j][pp] = xhc[(cr + j) * (size_t)D_INNER + h * 64 + pq * 16 + pp];
    }
    if (tid < 8) {
      float d = dtv[(gr + tid) * 32 + h];
      sdt[tid] = d;
      sdA[tid] = __expf(d * A);
    }
    __syncthreads();
#pragma unroll
    for (int j = 0; j < 8; ++j) {
      float dA = sdA[j];
      float dtj = sdt[j];
      float xv = sx[j][pl];
      float ccoef = dtj * xv;
      float4 bv = *(const float4*)&sB[j][n0];
      float4 cv = *(const float4*)&sC[j][n0];
      s0 = dA * s0 + ccoef * bv.x;
      s1 = dA * s1 + ccoef * bv.y;
      s2 = dA * s2 + ccoef * bv.z;
      s3 = dA * s3 + ccoef * bv.w;
      float acc2 = s0 * cv.x + s1 * cv.y + s2 * cv.z + s3 * cv.w;
      acc2 += __shfl_xor(acc2, 1);
      acc2 += __shfl_xor(acc2, 2);
      acc2 += __shfl_xor(acc2, 4);
      acc2 += __shfl_xor(acc2, 8);
      if ((tid & 15) == 0)
        y[(gr + j) * (size_t)D_INNER + h * 64 + p] = acc2 + Dh * xv;
    }
    __syncthreads();
  }
  state[sidx] = s0; state[sidx + 1] = s1; state[sidx + 2] = s2; state[sidx + 3] = s3;
}

// ---------------- gate (y * silu(z)) + RMSNorm * rms_w -> G hi/lo, IN PLACE in Y rows ----------
// Y row (2048 fp32 = 8 KB) is rewritten as [2048 bf16 hi][2048 bf16 lo]. Reads of the row
// complete (registers) before the post-reduction barrier; writes only after it.
__global__ __launch_bounds__(256) void gate_rms_kernel(const float* __restrict__ yf,
                                                       const unsigned short* __restrict__ zb,
                                                       const float* __restrict__ rw,
                                                       unsigned short* __restrict__ ghi) {
  int row = blockIdx.x, tid = threadIdx.x;
  const float* yr = yf + (size_t)row * D_INNER;
  const unsigned short* zr = zb + (size_t)row * D_INNER;
  float gv[8];
  float q = 0.f;
#pragma unroll
  for (int u = 0; u < 8; ++u) {
    int c = u * 256 + tid;
    float yv = yr[c];
    float zv = bf2f(zr[c]);
    float t = yv * (zv / (1.f + __expf(-zv)));
    gv[u] = t;
    q += t * t;
  }
  for (int off = 1; off < 64; off <<= 1) q += __shfl_xor(q, off);
  __shared__ float rq[4];
  if ((tid & 63) == 0) rq[tid >> 6] = q;
  __syncthreads();    // also guarantees all reads of this row are done before writes below
  q = rq[0] + rq[1] + rq[2] + rq[3];
  float scale = rsqrtf(q * (1.f / D_INNER) + EPS);
  unsigned short* gr = ghi + (size_t)row * 4096;
#pragma unroll
  for (int u = 0; u < 8; ++u) {
    int c = u * 256 + tid;
    unsigned short h, l;
    split_bf(gv[u] * scale * rw[c], h, l);
    gr[c] = h;
    gr[2048 + c] = l;
  }
}

extern "C" void kernel_launch(void* const* d_in, const int* in_sizes, int n_in,
                              void* d_out, int out_size, void* d_ws, size_t ws_size,
                              hipStream_t stream) {
  (void)in_sizes; (void)n_in; (void)out_size; (void)ws_size;
  const float* x     = (const float*)d_in[0];
  const float* ln_w  = (const float*)d_in[1];
  const float* ln_b  = (const float*)d_in[2];
  const float* w_in  = (const float*)d_in[3];
  const float* cw    = (const float*)d_in[4];
  const float* cb    = (const float*)d_in[5];
  const float* dtb   = (const float*)d_in[6];
  const float* alog  = (const float*)d_in[7];
  const float* dvec  = (const float*)d_in[8];
  const float* rmsw  = (const float*)d_in[9];
  const float* w_out = (const float*)d_in[10];
  float* out = (float*)d_out;

  // Workspace budget: known-good high-water mark 253.8 MB (R1 ran; R2 crashed at 287 MB).
  // Total here = 248.5 MB. REGION hosts LN hi/lo (ln->gemm1) then Y fp32 / G hi/lo
  // (scan->gemm2) — non-overlapping lifetimes. Layer-0 hidden state H lives in d_out.
  char* ws = (char*)d_ws;
  size_t off = 0;
  auto alloc = [&](size_t bytes) -> char* {
    char* p = ws + off;
    off += (bytes + 255) & ~(size_t)255;
    return p;
  };
  unsigned short* W1h = (unsigned short*)alloc(2ull * 2 * NPAD1 * 1024);   // 17.8 MB
  unsigned short* W1l = (unsigned short*)alloc(2ull * 2 * NPAD1 * 1024);   // 17.8 MB
  unsigned short* W2h = (unsigned short*)alloc(2ull * 2 * 1024 * 2048);    //  8.4 MB
  unsigned short* W2l = (unsigned short*)alloc(2ull * 2 * 1024 * 2048);    //  8.4 MB
  char* REGION = alloc(4ull * BL * D_INNER);                               // 67.1 MB
  unsigned short* LNh = (unsigned short*)REGION;                           //  (16.8)
  unsigned short* LNl = (unsigned short*)(REGION + 2ull * BL * D_MODEL);   //  (16.8)
  float* Yf = (float*)REGION;                                              //  (67.1)
  unsigned short* Zb = (unsigned short*)alloc(2ull * BL * D_INNER);        // 33.6 MB
  float* XPRE = (float*)alloc(4ull * BL * D_INNER);                        // 67.1 MB
  float* AUX  = (float*)alloc(4ull * BL * 160);                            //  5.2 MB
  float* XHC  = (float*)alloc(4ull * 2 * CH * D_INNER);                    // 16.8 MB
  float* BC = (float*)alloc(4ull * BL * D_STATE);                          //  2.1 MB
  float* CC = (float*)alloc(4ull * BL * D_STATE);                          //  2.1 MB
  float* DT = (float*)alloc(4ull * BL * NHEADS);                           //  1.0 MB
  float* STATE = (float*)alloc(4ull * 256 * 256 * 4);                      //  1.0 MB

  cvt_w1_kernel<<<(2 * NPAD1 * 1024) / 256, 256, 0, stream>>>(w_in, W1h, W1l);
  cvt_w2_kernel<<<(2 * 1024 * 2048) / 256, 256, 0, stream>>>(w_out, W2h, W2l);

  for (int layer = 0; layer < 2; ++layer) {
    const float* hin = layer ? (const float*)out : x;
    size_t o1 = (size_t)layer * NPAD1 * 1024;
    size_t o2 = (size_t)layer * 1024 * 2048;
    ln_kernel<<<BL, 256, 0, stream>>>(hin, ln_w + layer * D_MODEL, ln_b + layer * D_MODEL,
                                      LNh, LNl);
    gemm_split_kernel<0><<<dim3(NPAD1 / 128, BL / 128), 256, 0, stream>>>(
        LNh, LNl, 1024, W1h + o1, W1l + o1, 1024, Zb, XPRE, AUX, nullptr, nullptr);
    dt_kernel<<<(BL * NHEADS) / 256, 256, 0, stream>>>(AUX, dtb + layer * NHEADS, DT);
    for (int k = 0; k < LSEQ / CH; ++k) {
      conv_chunk_kernel<<<dim3(2 * CH, 9), 256, 0, stream>>>(
          XPRE, AUX, cw + layer * CONV_DIM * 4, cb + layer * CONV_DIM, k * CH, XHC, BC, CC);
      scan_chunk_kernel<<<256, 256, 0, stream>>>(
          XHC, BC, CC, DT, alog + layer * NHEADS, dvec + layer * NHEADS, k * CH, STATE, Yf);
    }
    gate_rms_kernel<<<BL, 256, 0, stream>>>(Yf, Zb, rmsw + layer * D_INNER,
                                            (unsigned short*)Yf);
    gemm_split_kernel<1><<<dim3(1024 / 128, BL / 128), 256, 0, stream>>>(
        (unsigned short*)Yf, (unsigned short*)Yf + 2048, 4096, W2h + o2, W2l + o2, 2048,
        nullptr, nullptr, nullptr, out, hin);
  }
}

// Round 5
// 1777.317 us; speedup vs baseline: 2.0579x; 2.0579x over previous
//
#include <hip/hip_runtime.h>
#include <stdint.h>

#define D_MODEL   1024
#define D_STATE   64
#define D_INNER   2048
#define NHEADS    32
#define CONV_DIM  2176
#define D_IN_PROJ 4256
#define NPAD1     4352   // 34*128, padded N for in_proj GEMM
#define LSEQ      4096
#define BL        8192   // B*L
#define CH        1024   // conv/scan time-chunk length
#define EPS       1e-5f

typedef __attribute__((ext_vector_type(8))) __bf16 bf16x8;
typedef __attribute__((ext_vector_type(4))) float f32x4;

__device__ __forceinline__ unsigned short f2bf(float f) {
  union { float f; unsigned u; } v; v.f = f;
  unsigned r = v.u + 0x7fffu + ((v.u >> 16) & 1u);   // RNE
  return (unsigned short)(r >> 16);
}
__device__ __forceinline__ float bf2f(unsigned short h) {
  union { unsigned u; float f; } v; v.u = (unsigned)h << 16;
  return v.f;
}
__device__ __forceinline__ void split_bf(float x, unsigned short& hi, unsigned short& lo) {
  hi = f2bf(x);
  lo = f2bf(x - bf2f(hi));
}
__device__ __forceinline__ void load_lds16(const void* g, void* l) {
  __builtin_amdgcn_global_load_lds((const __attribute__((address_space(1))) void*)g,
                                   (__attribute__((address_space(3))) void*)l, 16, 0, 0);
}

// ---------------- weight casts: fp32 -> bf16 hi/lo pairs ----------------
__global__ __launch_bounds__(256) void cvt_w1_kernel(const float* __restrict__ w,
                                                     unsigned short* __restrict__ hi,
                                                     unsigned short* __restrict__ lo) {
  size_t idx = (size_t)blockIdx.x * 256 + threadIdx.x;   // over 2*4352*1024
  int k = idx & 1023;
  size_t nr = idx >> 10;
  int layer = (int)(nr / NPAD1);
  int n = (int)(nr % NPAD1);
  float v = (n < D_IN_PROJ) ? w[((size_t)layer * D_IN_PROJ + n) * 1024 + k] : 0.f;
  unsigned short h, l; split_bf(v, h, l);
  hi[idx] = h; lo[idx] = l;
}
__global__ __launch_bounds__(256) void cvt_w2_kernel(const float* __restrict__ w,
                                                     unsigned short* __restrict__ hi,
                                                     unsigned short* __restrict__ lo) {
  size_t idx = (size_t)blockIdx.x * 256 + threadIdx.x;   // over 2*1024*2048
  unsigned short h, l; split_bf(w[idx], h, l);
  hi[idx] = h; lo[idx] = l;
}

// ---------------- layernorm (row of 1024), fp32 in -> bf16 hi/lo out ----------------
__global__ __launch_bounds__(256) void ln_kernel(const float* __restrict__ x,
                                                 const float* __restrict__ w,
                                                 const float* __restrict__ b,
                                                 unsigned short* __restrict__ ohi,
                                                 unsigned short* __restrict__ olo) {
  int row = blockIdx.x, tid = threadIdx.x;
  const float* xr = x + (size_t)row * D_MODEL;
  float4 v = *(const float4*)(xr + tid * 4);
  float s = v.x + v.y + v.z + v.w;
  float q = v.x * v.x + v.y * v.y + v.z * v.z + v.w * v.w;
  for (int off = 1; off < 64; off <<= 1) { s += __shfl_xor(s, off); q += __shfl_xor(q, off); }
  __shared__ float rs[4], rq[4];
  int wave = tid >> 6, lane = tid & 63;
  if (lane == 0) { rs[wave] = s; rq[wave] = q; }
  __syncthreads();
  s = rs[0] + rs[1] + rs[2] + rs[3];
  q = rq[0] + rq[1] + rq[2] + rq[3];
  float mean = s * (1.f / D_MODEL);
  float var = q * (1.f / D_MODEL) - mean * mean;
  float rstd = rsqrtf(var + EPS);
  int c = tid * 4;
  ushort4 hv, lv;
  float y0 = (v.x - mean) * rstd * w[c + 0] + b[c + 0];
  float y1 = (v.y - mean) * rstd * w[c + 1] + b[c + 1];
  float y2 = (v.z - mean) * rstd * w[c + 2] + b[c + 2];
  float y3 = (v.w - mean) * rstd * w[c + 3] + b[c + 3];
  split_bf(y0, hv.x, lv.x); split_bf(y1, hv.y, lv.y);
  split_bf(y2, hv.z, lv.z); split_bf(y3, hv.w, lv.w);
  *(ushort4*)(ohi + (size_t)row * D_MODEL + c) = hv;
  *(ushort4*)(olo + (size_t)row * D_MODEL + c) = lv;
}

// ---------------- split-bf16 GEMM (bf16x3): C = (Ahi+Alo)(Bhi+Blo)^T ----------------
// 128x128 tile, BK=32, 4 waves. MODE 0: in_proj epilogue (z bf16 / xpre fp32 / aux fp32).
// MODE 1: fp32 out + fp32 resid (out_proj).
template <int MODE>
__global__ __launch_bounds__(256) void gemm_split_kernel(
    const unsigned short* __restrict__ Ahi, const unsigned short* __restrict__ Alo, int lda,
    const unsigned short* __restrict__ Bhi, const unsigned short* __restrict__ Blo, int K,
    unsigned short* __restrict__ Zb, float* __restrict__ XPRE, float* __restrict__ AUX,
    float* __restrict__ Cf, const float* __restrict__ resid) {
  __shared__ unsigned short lAh[128 * 32], lAl[128 * 32];
  __shared__ unsigned short lBh[128 * 32], lBl[128 * 32];
  int tid = threadIdx.x;
  int wave = tid >> 6, lane = tid & 63;
  int bn = blockIdx.x, bm = blockIdx.y;
  const int rA = lane >> 2;
  const int cA = (lane & 3) * 8;     // LDS byte dest = wave-uniform + lane*16 (HW reqt)
  const int wm = (wave >> 1) * 64, wn = (wave & 1) * 64;
  const int fr = lane & 15;
  const int fk = (lane >> 4) * 8;
  size_t aoff = (size_t)(bm * 128) * lda;
  size_t boff = (size_t)(bn * 128) * K;
  f32x4 acc[4][4];
  f32x4 zero = {0.f, 0.f, 0.f, 0.f};
#pragma unroll
  for (int i = 0; i < 4; ++i)
#pragma unroll
    for (int j = 0; j < 4; ++j) acc[i][j] = zero;

  for (int k0 = 0; k0 < K; k0 += 32) {
#pragma unroll
    for (int c = 0; c < 2; ++c) {
      int row = (wave * 2 + c) * 16 + rA;
      size_t ga = aoff + (size_t)row * lda + k0 + cA;
      size_t gb = boff + (size_t)row * K + k0 + cA;
      load_lds16(Ahi + ga, &lAh[row * 32 + cA]);
      load_lds16(Alo + ga, &lAl[row * 32 + cA]);
      load_lds16(Bhi + gb, &lBh[row * 32 + cA]);
      load_lds16(Blo + gb, &lBl[row * 32 + cA]);
    }
    __syncthreads();
    bf16x8 ah[4], al[4], bh[4], bl[4];
#pragma unroll
    for (int i = 0; i < 4; ++i) {
      ah[i] = *(const bf16x8*)&lAh[(wm + i * 16 + fr) * 32 + fk];
      al[i] = *(const bf16x8*)&lAl[(wm + i * 16 + fr) * 32 + fk];
    }
#pragma unroll
    for (int j = 0; j < 4; ++j) {
      bh[j] = *(const bf16x8*)&lBh[(wn + j * 16 + fr) * 32 + fk];
      bl[j] = *(const bf16x8*)&lBl[(wn + j * 16 + fr) * 32 + fk];
    }
#pragma unroll
    for (int i = 0; i < 4; ++i)
#pragma unroll
      for (int j = 0; j < 4; ++j) {
        acc[i][j] = __builtin_amdgcn_mfma_f32_16x16x32_bf16(al[i], bh[j], acc[i][j], 0, 0, 0);
        acc[i][j] = __builtin_amdgcn_mfma_f32_16x16x32_bf16(ah[i], bl[j], acc[i][j], 0, 0, 0);
        acc[i][j] = __builtin_amdgcn_mfma_f32_16x16x32_bf16(ah[i], bh[j], acc[i][j], 0, 0, 0);
      }
    __syncthreads();
  }
  // epilogue: D layout col=lane&15, row=(lane>>4)*4+reg
  int r0 = (lane >> 4) * 4;
  int cc = lane & 15;
#pragma unroll
  for (int i = 0; i < 4; ++i) {
#pragma unroll
    for (int j = 0; j < 4; ++j) {
      int col = bn * 128 + wn + j * 16 + cc;
#pragma unroll
      for (int r = 0; r < 4; ++r) {
        size_t row = (size_t)(bm * 128 + wm + i * 16 + r0 + r);
        float v = acc[i][j][r];
        if constexpr (MODE == 0) {
          if (col < 2048)       Zb[row * 2048 + col] = f2bf(v);
          else if (col < 4096)  XPRE[row * 2048 + (col - 2048)] = v;
          else if (col < 4256)  AUX[row * 160 + (col - 4096)] = v;
        } else {
          size_t idx = row * 1024 + col;
          Cf[idx] = v + resid[idx];
        }
      }
    }
  }
}

// ---------------- dt = softplus(dt_raw + dt_bias) + dA = exp(dt*A), transposed [h][l] -------
__global__ __launch_bounds__(256) void dt_kernel(const float* __restrict__ aux,
                                                 const float* __restrict__ dtb,
                                                 const float* __restrict__ alog,
                                                 float* __restrict__ dtt,
                                                 float* __restrict__ da) {
  int idx = blockIdx.x * 256 + threadIdx.x;   // over 32*8192, h-major
  int h = idx >> 13, l = idx & 8191;
  float A = -__expf(alog[h]);                 // A = -exp(A_log); __expf IS e^x
  float v = aux[(size_t)l * 160 + 128 + h] + dtb[h];
  float sp = (v > 20.f) ? v : log1pf(expf(v));
  dtt[idx] = sp;
  da[idx] = __expf(sp * A);
}

// ---------------- causal depthwise conv (width 4) + bias + silu, one time-chunk ----------------
__global__ __launch_bounds__(256) void conv_chunk_kernel(const float* __restrict__ xpre,
                                                         const float* __restrict__ aux,
                                                         const float* __restrict__ cw,
                                                         const float* __restrict__ cb,
                                                         int t0,
                                                         float* __restrict__ xhc,
                                                         float* __restrict__ Bo,
                                                         float* __restrict__ Co) {
  int lr = blockIdx.x;                      // 0..2*CH-1 chunk-local row
  int c = blockIdx.y * 256 + threadIdx.x;
  if (c >= CONV_DIM) return;
  int b = lr >> 10, tl = lr & (CH - 1);
  int t = t0 + tl;
  int l = b * LSEQ + t;                     // global row
  float acc = cb[c];
#pragma unroll
  for (int j = 0; j < 4; ++j) {
    int tt = t - 3 + j;
    if (tt >= 0) {
      size_t ll = (size_t)(b * LSEQ + tt);
      float xv = (c < 2048) ? xpre[ll * 2048 + c] : aux[ll * 160 + (c - 2048)];
      acc += xv * cw[c * 4 + j];
    }
  }
  acc = acc / (1.f + __expf(-acc));   // silu
  if (c < D_INNER)
    xhc[(size_t)lr * D_INNER + c] = acc;
  else if (c < D_INNER + D_STATE)
    Bo[(size_t)l * D_STATE + (c - D_INNER)] = acc;
  else
    Co[(size_t)l * D_STATE + (c - D_INNER - D_STATE)] = acc;
}

// ---------------- sequential SSM scan, one time-chunk, state carried in ws ----------------
// grid 256: (b, h, p-quarter). Thread: pl=tid>>4 (local p row), nq=tid&15 (n quad).
// 16-step groups, double-buffered global_load_lds staging; per-step dot partials go to
// LDS and are reduced in a batched pass (keeps the sequential critical path = 1 FMA).
__global__ __launch_bounds__(256) void scan_chunk_kernel(const float* __restrict__ xhc,
                                                         const float* __restrict__ Bc,
                                                         const float* __restrict__ Cc,
                                                         const float* __restrict__ dtt,
                                                         const float* __restrict__ dac,
                                                         const float* __restrict__ Dv,
                                                         int t0,
                                                         float* __restrict__ state,
                                                         float* __restrict__ y) {
  int bid = blockIdx.x;
  int b = bid >> 7, h = (bid >> 2) & 31, pq = bid & 3;
  int tid = threadIdx.x;
  int pl = tid >> 4;
  int nq = tid & 15;
  int n0 = nq * 4;
  float Dh = Dv[h];
  size_t sidx = ((size_t)bid * 256 + tid) * 4;
  float s0, s1, s2, s3;
  if (t0 == 0) { s0 = s1 = s2 = s3 = 0.f; }
  else { float4 sv = *(const float4*)&state[sidx]; s0 = sv.x; s1 = sv.y; s2 = sv.z; s3 = sv.w; }

  __shared__ float sB[2][1024], sC[2][1024];   // [buf][16 steps][64 n]
  __shared__ float sx[2][256];                 // [buf][16 steps][16 p]
  __shared__ float sdtA[2][32];                // [buf][step*2 + {0:dt,1:dA}]
  __shared__ float part[16][16][20];           // [step][p][nq] (+pad: 80B rows, 2-way banks)

  const float* dtp = dtt + (size_t)h * BL;
  const float* dap = dac + (size_t)h * BL;
  size_t gb = (size_t)b * LSEQ + t0;   // global row base of this chunk (B/C/dt/y)
  size_t cb = (size_t)b * CH;          // xhc chunk-local row base
  const int xcol = h * 64 + pq * 16;

  auto issueBCx = [&](int g, int nb) {
    size_t rbc = (gb + g * 16 + (tid >> 4)) * 64 + (tid & 15) * 4;
    load_lds16(Bc + rbc, &sB[nb][tid * 4]);    // dest = lane*16B linear: DMA constraint OK
    load_lds16(Cc + rbc, &sC[nb][tid * 4]);
    if (tid < 64)
      load_lds16(xhc + (cb + g * 16 + (tid >> 2)) * (size_t)D_INNER + xcol + (tid & 3) * 4,
                 &sx[nb][tid * 4]);
  };

  // prologue: group 0
  float dreg0 = 0.f;
  if (tid < 32) dreg0 = ((tid & 1) ? dap : dtp)[gb + (tid >> 1)];
  issueBCx(0, 0);
  if (tid < 32) sdtA[0][tid] = dreg0;
  __syncthreads();

  const int ngroups = CH / 16;
  for (int g = 0; g < ngroups; ++g) {
    int buf = g & 1, nbuf = buf ^ 1;
    float dreg = 0.f;
    bool pf = (g + 1 < ngroups);
    if (pf) {
      issueBCx(g + 1, nbuf);
      if (tid < 32) dreg = ((tid & 1) ? dap : dtp)[gb + (g + 1) * 16 + (tid >> 1)];
    }
#pragma unroll
    for (int j = 0; j < 16; ++j) {
      float2 dd = *(const float2*)&sdtA[buf][2 * j];   // x=dt, y=dA
      float xv = sx[buf][j * 16 + pl];
      float cf = dd.x * xv;
      float4 bv = *(const float4*)&sB[buf][j * 64 + n0];
      float4 cv = *(const float4*)&sC[buf][j * 64 + n0];
      s0 = dd.y * s0 + cf * bv.x;
      s1 = dd.y * s1 + cf * bv.y;
      s2 = dd.y * s2 + cf * bv.z;
      s3 = dd.y * s3 + cf * bv.w;
      part[j][pl][nq] = s0 * cv.x + s1 * cv.y + s2 * cv.z + s3 * cv.w;
    }
    if (pf && tid < 32) sdtA[nbuf][tid] = dreg;
    __syncthreads();   // partials visible; prefetched async loads also drained here
    {
      int jj = tid >> 4, pp = tid & 15;
      const float4* pr = (const float4*)&part[jj][pp][0];
      float4 a0 = pr[0], a1 = pr[1], a2 = pr[2], a3 = pr[3];
      float sum = (((a0.x + a0.y) + (a0.z + a0.w)) + ((a1.x + a1.y) + (a1.z + a1.w)))
                + (((a2.x + a2.y) + (a2.z + a2.w)) + ((a3.x + a3.y) + (a3.z + a3.w)));
      float xv2 = sx[buf][jj * 16 + pp];
      y[(gb + g * 16 + jj) * (size_t)D_INNER + h * 64 + pq * 16 + pp] = sum + Dh * xv2;
    }
    __syncthreads();   // part/buffers reusable
  }
  float4 sv = {s0, s1, s2, s3};
  *(float4*)&state[sidx] = sv;
}

// ---------------- gate (y * silu(z)) + RMSNorm * rms_w -> G hi/lo, IN PLACE in Y rows ----------
__global__ __launch_bounds__(256) void gate_rms_kernel(const float* __restrict__ yf,
                                                       const unsigned short* __restrict__ zb,
                                                       const float* __restrict__ rw,
                                                       unsigned short* __restrict__ ghi) {
  int row = blockIdx.x, tid = threadIdx.x;
  const float* yr = yf + (size_t)row * D_INNER;
  const unsigned short* zr = zb + (size_t)row * D_INNER;
  float gv[8];
  float q = 0.f;
#pragma unroll
  for (int u = 0; u < 8; ++u) {
    int c = u * 256 + tid;
    float yv = yr[c];
    float zv = bf2f(zr[c]);
    float t = yv * (zv / (1.f + __expf(-zv)));
    gv[u] = t;
    q += t * t;
  }
  for (int off = 1; off < 64; off <<= 1) q += __shfl_xor(q, off);
  __shared__ float rq[4];
  if ((tid & 63) == 0) rq[tid >> 6] = q;
  __syncthreads();    // also guarantees all reads of this row are done before writes below
  q = rq[0] + rq[1] + rq[2] + rq[3];
  float scale = rsqrtf(q * (1.f / D_INNER) + EPS);
  unsigned short* gr = ghi + (size_t)row * 4096;
#pragma unroll
  for (int u = 0; u < 8; ++u) {
    int c = u * 256 + tid;
    unsigned short h, l;
    split_bf(gv[u] * scale * rw[c], h, l);
    gr[c] = h;
    gr[2048 + c] = l;
  }
}

extern "C" void kernel_launch(void* const* d_in, const int* in_sizes, int n_in,
                              void* d_out, int out_size, void* d_ws, size_t ws_size,
                              hipStream_t stream) {
  (void)in_sizes; (void)n_in; (void)out_size; (void)ws_size;
  const float* x     = (const float*)d_in[0];
  const float* ln_w  = (const float*)d_in[1];
  const float* ln_b  = (const float*)d_in[2];
  const float* w_in  = (const float*)d_in[3];
  const float* cw    = (const float*)d_in[4];
  const float* cb    = (const float*)d_in[5];
  const float* dtb   = (const float*)d_in[6];
  const float* alog  = (const float*)d_in[7];
  const float* dvec  = (const float*)d_in[8];
  const float* rmsw  = (const float*)d_in[9];
  const float* w_out = (const float*)d_in[10];
  float* out = (float*)d_out;

  // Workspace budget: known-good high-water mark 253.8 MB (R2 crashed at 287 MB).
  // Total here ≈ 249.5 MB. REGION hosts LN hi/lo (ln->gemm1) then Y fp32 / G hi/lo
  // (scan->gemm2) — non-overlapping lifetimes. Layer-0 hidden state H lives in d_out.
  char* ws = (char*)d_ws;
  size_t off = 0;
  auto alloc = [&](size_t bytes) -> char* {
    char* p = ws + off;
    off += (bytes + 255) & ~(size_t)255;
    return p;
  };
  unsigned short* W1h = (unsigned short*)alloc(2ull * 2 * NPAD1 * 1024);   // 17.8 MB
  unsigned short* W1l = (unsigned short*)alloc(2ull * 2 * NPAD1 * 1024);   // 17.8 MB
  unsigned short* W2h = (unsigned short*)alloc(2ull * 2 * 1024 * 2048);    //  8.4 MB
  unsigned short* W2l = (unsigned short*)alloc(2ull * 2 * 1024 * 2048);    //  8.4 MB
  char* REGION = alloc(4ull * BL * D_INNER);                               // 67.1 MB
  unsigned short* LNh = (unsigned short*)REGION;                           //  (16.8)
  unsigned short* LNl = (unsigned short*)(REGION + 2ull * BL * D_MODEL);   //  (16.8)
  float* Yf = (float*)REGION;                                              //  (67.1)
  unsigned short* Zb = (unsigned short*)alloc(2ull * BL * D_INNER);        // 33.6 MB
  float* XPRE = (float*)alloc(4ull * BL * D_INNER);                        // 67.1 MB
  float* AUX  = (float*)alloc(4ull * BL * 160);                            //  5.2 MB
  float* XHC  = (float*)alloc(4ull * 2 * CH * D_INNER);                    // 16.8 MB
  float* BC = (float*)alloc(4ull * BL * D_STATE);                          //  2.1 MB
  float* CC = (float*)alloc(4ull * BL * D_STATE);                          //  2.1 MB
  float* DTt = (float*)alloc(4ull * NHEADS * BL);                          //  1.0 MB
  float* DA  = (float*)alloc(4ull * NHEADS * BL);                          //  1.0 MB
  float* STATE = (float*)alloc(4ull * 256 * 256 * 4);                      //  1.0 MB

  cvt_w1_kernel<<<(2 * NPAD1 * 1024) / 256, 256, 0, stream>>>(w_in, W1h, W1l);
  cvt_w2_kernel<<<(2 * 1024 * 2048) / 256, 256, 0, stream>>>(w_out, W2h, W2l);

  for (int layer = 0; layer < 2; ++layer) {
    const float* hin = layer ? (const float*)out : x;
    size_t o1 = (size_t)layer * NPAD1 * 1024;
    size_t o2 = (size_t)layer * 1024 * 2048;
    ln_kernel<<<BL, 256, 0, stream>>>(hin, ln_w + layer * D_MODEL, ln_b + layer * D_MODEL,
                                      LNh, LNl);
    gemm_split_kernel<0><<<dim3(NPAD1 / 128, BL / 128), 256, 0, stream>>>(
        LNh, LNl, 1024, W1h + o1, W1l + o1, 1024, Zb, XPRE, AUX, nullptr, nullptr);
    dt_kernel<<<(NHEADS * BL) / 256, 256, 0, stream>>>(AUX, dtb + layer * NHEADS,
                                                       alog + layer * NHEADS, DTt, DA);
    for (int k = 0; k < LSEQ / CH; ++k) {
      conv_chunk_kernel<<<dim3(2 * CH, 9), 256, 0, stream>>>(
          XPRE, AUX, cw + layer * CONV_DIM * 4, cb + layer * CONV_DIM, k * CH, XHC, BC, CC);
      scan_chunk_kernel<<<256, 256, 0, stream>>>(
          XHC, BC, CC, DTt, DA, dvec + layer * NHEADS, k * CH, STATE, Yf);
    }
    gate_rms_kernel<<<BL, 256, 0, stream>>>(Yf, Zb, rmsw + layer * D_INNER,
                                            (unsigned short*)Yf);
    gemm_split_kernel<1><<<dim3(1024 / 128, BL / 128), 256, 0, stream>>>(
        (unsigned short*)Yf, (unsigned short*)Yf + 2048, 4096, W2h + o2, W2l + o2, 2048,
        nullptr, nullptr, nullptr, out, hin);
  }
}

// Round 6
// 1395.131 us; speedup vs baseline: 2.6216x; 1.2739x over previous
//
#include <hip/hip_runtime.h>
#include <stdint.h>

#define D_MODEL   1024
#define D_STATE   64
#define D_INNER   2048
#define NHEADS    32
#define CONV_DIM  2176
#define D_IN_PROJ 4256
#define NPAD1     4352   // 34*128, padded N for in_proj GEMM
#define LSEQ      4096
#define BL        8192   // B*L
#define CH        1024   // conv/scan time-chunk length
#define EPS       1e-5f

typedef __attribute__((ext_vector_type(8))) _Float16 f16x8;
typedef __attribute__((ext_vector_type(4))) _Float16 f16x4;
typedef __attribute__((ext_vector_type(4))) float f32x4;

__device__ __forceinline__ void load_lds16(const void* g, void* l) {
  __builtin_amdgcn_global_load_lds((const __attribute__((address_space(1))) void*)g,
                                   (__attribute__((address_space(3))) void*)l, 16, 0, 0);
}

// ---------------- weight casts: fp32 -> fp16 ----------------
__global__ __launch_bounds__(256) void cvt_w1_kernel(const float* __restrict__ w,
                                                     _Float16* __restrict__ o) {
  size_t idx = (size_t)blockIdx.x * 256 + threadIdx.x;   // over 2*4352*1024
  int k = idx & 1023;
  size_t nr = idx >> 10;
  int layer = (int)(nr / NPAD1);
  int n = (int)(nr % NPAD1);
  float v = (n < D_IN_PROJ) ? w[((size_t)layer * D_IN_PROJ + n) * 1024 + k] : 0.f;
  o[idx] = (_Float16)v;
}
__global__ __launch_bounds__(256) void cvt_w2_kernel(const float* __restrict__ w,
                                                     _Float16* __restrict__ o) {
  size_t idx = (size_t)blockIdx.x * 256 + threadIdx.x;   // over 2*1024*2048
  o[idx] = (_Float16)w[idx];
}

// ---------------- layernorm (row of 1024), fp32 in -> fp16 out ----------------
__global__ __launch_bounds__(256) void ln_kernel(const float* __restrict__ x,
                                                 const float* __restrict__ w,
                                                 const float* __restrict__ b,
                                                 _Float16* __restrict__ o) {
  int row = blockIdx.x, tid = threadIdx.x;
  const float* xr = x + (size_t)row * D_MODEL;
  float4 v = *(const float4*)(xr + tid * 4);
  float s = v.x + v.y + v.z + v.w;
  float q = v.x * v.x + v.y * v.y + v.z * v.z + v.w * v.w;
  for (int off = 1; off < 64; off <<= 1) { s += __shfl_xor(s, off); q += __shfl_xor(q, off); }
  __shared__ float rs[4], rq[4];
  int wave = tid >> 6, lane = tid & 63;
  if (lane == 0) { rs[wave] = s; rq[wave] = q; }
  __syncthreads();
  s = rs[0] + rs[1] + rs[2] + rs[3];
  q = rq[0] + rq[1] + rq[2] + rq[3];
  float mean = s * (1.f / D_MODEL);
  float var = q * (1.f / D_MODEL) - mean * mean;
  float rstd = rsqrtf(var + EPS);
  int c = tid * 4;
  f16x4 ov;
  ov[0] = (_Float16)((v.x - mean) * rstd * w[c + 0] + b[c + 0]);
  ov[1] = (_Float16)((v.y - mean) * rstd * w[c + 1] + b[c + 1]);
  ov[2] = (_Float16)((v.z - mean) * rstd * w[c + 2] + b[c + 2]);
  ov[3] = (_Float16)((v.w - mean) * rstd * w[c + 3] + b[c + 3]);
  *(f16x4*)(o + (size_t)row * D_MODEL + c) = ov;
}

// ---------------- fp16 GEMM, C[m,n] = sum_k A[m,k]*B[n,k]  (m97 structure) ----------------
// 128x128 tile, BK=32, 4 waves (2x2 of 64x64), 16x16x32 f16 MFMA, fp32 accum.
// MODE 0: in_proj epilogue (z fp16 / xpre fp16 / aux fp32). MODE 1: fp32 out + resid.
template <int MODE>
__global__ __launch_bounds__(256) void gemm_f16_kernel(
    const _Float16* __restrict__ A, int lda,
    const _Float16* __restrict__ Bw, int K,
    _Float16* __restrict__ Zb, _Float16* __restrict__ XPRE, float* __restrict__ AUX,
    float* __restrict__ Cf, const float* __restrict__ resid) {
  __shared__ _Float16 lA[128 * 32];
  __shared__ _Float16 lB[128 * 32];
  int tid = threadIdx.x;
  int wave = tid >> 6, lane = tid & 63;
  int bn = blockIdx.x, bm = blockIdx.y;
  const int rA = lane >> 2;          // row within a 16-row staging chunk
  const int cA = (lane & 3) * 8;     // k-element offset (16B per lane; DMA lane-linear dest)
  const int wm = (wave >> 1) * 64, wn = (wave & 1) * 64;
  const int fr = lane & 15;
  const int fk = (lane >> 4) * 8;
  size_t aoff = (size_t)(bm * 128) * lda;
  size_t boff = (size_t)(bn * 128) * K;
  f32x4 acc[4][4];
  f32x4 zero = {0.f, 0.f, 0.f, 0.f};
#pragma unroll
  for (int i = 0; i < 4; ++i)
#pragma unroll
    for (int j = 0; j < 4; ++j) acc[i][j] = zero;

  for (int k0 = 0; k0 < K; k0 += 32) {
#pragma unroll
    for (int c = 0; c < 2; ++c) {
      int row = (wave * 2 + c) * 16 + rA;
      load_lds16(A + aoff + (size_t)row * lda + k0 + cA, &lA[row * 32 + cA]);
      load_lds16(Bw + boff + (size_t)row * K + k0 + cA, &lB[row * 32 + cA]);
    }
    __syncthreads();
    f16x8 af[4], bf[4];
#pragma unroll
    for (int i = 0; i < 4; ++i) af[i] = *(const f16x8*)&lA[(wm + i * 16 + fr) * 32 + fk];
#pragma unroll
    for (int j = 0; j < 4; ++j) bf[j] = *(const f16x8*)&lB[(wn + j * 16 + fr) * 32 + fk];
#pragma unroll
    for (int i = 0; i < 4; ++i)
#pragma unroll
      for (int j = 0; j < 4; ++j)
        acc[i][j] = __builtin_amdgcn_mfma_f32_16x16x32_f16(af[i], bf[j], acc[i][j], 0, 0, 0);
    __syncthreads();
  }
  // epilogue: D layout col=lane&15, row=(lane>>4)*4+reg
  int r0 = (lane >> 4) * 4;
  int cc = lane & 15;
#pragma unroll
  for (int i = 0; i < 4; ++i) {
#pragma unroll
    for (int j = 0; j < 4; ++j) {
      int col = bn * 128 + wn + j * 16 + cc;
#pragma unroll
      for (int r = 0; r < 4; ++r) {
        size_t row = (size_t)(bm * 128 + wm + i * 16 + r0 + r);
        float v = acc[i][j][r];
        if constexpr (MODE == 0) {
          if (col < 2048)       Zb[row * 2048 + col] = (_Float16)v;
          else if (col < 4096)  XPRE[row * 2048 + (col - 2048)] = (_Float16)v;
          else if (col < 4256)  AUX[row * 160 + (col - 4096)] = v;
        } else {
          size_t idx = row * 1024 + col;
          Cf[idx] = v + resid[idx];
        }
      }
    }
  }
}

// ---------------- dt = softplus(dt_raw + dt_bias) + dA = exp(dt*A), transposed [h][l] -------
__global__ __launch_bounds__(256) void dt_kernel(const float* __restrict__ aux,
                                                 const float* __restrict__ dtb,
                                                 const float* __restrict__ alog,
                                                 float* __restrict__ dtt,
                                                 float* __restrict__ da) {
  int idx = blockIdx.x * 256 + threadIdx.x;   // over 32*8192, h-major
  int h = idx >> 13, l = idx & 8191;
  float A = -__expf(alog[h]);                 // A = -exp(A_log); __expf IS e^x
  float v = aux[(size_t)l * 160 + 128 + h] + dtb[h];
  float sp = (v > 20.f) ? v : log1pf(expf(v));
  dtt[idx] = sp;
  da[idx] = __expf(sp * A);
}

// ---------------- causal depthwise conv (width 4) + bias + silu, one time-chunk ----------------
__global__ __launch_bounds__(256) void conv_chunk_kernel(const _Float16* __restrict__ xpre,
                                                         const float* __restrict__ aux,
                                                         const float* __restrict__ cw,
                                                         const float* __restrict__ cb,
                                                         int t0,
                                                         float* __restrict__ xhc,
                                                         float* __restrict__ Bo,
                                                         float* __restrict__ Co) {
  int lr = blockIdx.x;                      // 0..2*CH-1 chunk-local row
  int c = blockIdx.y * 256 + threadIdx.x;
  if (c >= CONV_DIM) return;
  int b = lr >> 10, tl = lr & (CH - 1);
  int t = t0 + tl;
  int l = b * LSEQ + t;                     // global row
  float acc = cb[c];
#pragma unroll
  for (int j = 0; j < 4; ++j) {
    int tt = t - 3 + j;
    if (tt >= 0) {
      size_t ll = (size_t)(b * LSEQ + tt);
      float xv = (c < 2048) ? (float)xpre[ll * 2048 + c] : aux[ll * 160 + (c - 2048)];
      acc += xv * cw[c * 4 + j];
    }
  }
  acc = acc / (1.f + __expf(-acc));   // silu
  if (c < D_INNER)
    xhc[(size_t)lr * D_INNER + c] = acc;
  else if (c < D_INNER + D_STATE)
    Bo[(size_t)l * D_STATE + (c - D_INNER)] = acc;
  else
    Co[(size_t)l * D_STATE + (c - D_INNER - D_STATE)] = acc;
}

// ---------------- sequential SSM scan, one time-chunk, state carried in ws ----------------
// grid 256: (b, h, p-quarter). Thread: pl=tid>>4 (local p row), nq=tid&15 (n quad).
// 16-step groups, double-buffered global_load_lds staging; per-step dot partials go to
// LDS and are reduced in a batched pass (keeps the sequential critical path = 1 FMA).
__global__ __launch_bounds__(256) void scan_chunk_kernel(const float* __restrict__ xhc,
                                                         const float* __restrict__ Bc,
                                                         const float* __restrict__ Cc,
                                                         const float* __restrict__ dtt,
                                                         const float* __restrict__ dac,
                                                         const float* __restrict__ Dv,
                                                         int t0,
                                                         float* __restrict__ state,
                                                         float* __restrict__ y) {
  int bid = blockIdx.x;
  int b = bid >> 7, h = (bid >> 2) & 31, pq = bid & 3;
  int tid = threadIdx.x;
  int pl = tid >> 4;
  int nq = tid & 15;
  int n0 = nq * 4;
  float Dh = Dv[h];
  size_t sidx = ((size_t)bid * 256 + tid) * 4;
  float s0, s1, s2, s3;
  if (t0 == 0) { s0 = s1 = s2 = s3 = 0.f; }
  else { float4 sv = *(const float4*)&state[sidx]; s0 = sv.x; s1 = sv.y; s2 = sv.z; s3 = sv.w; }

  __shared__ float sB[2][1024], sC[2][1024];   // [buf][16 steps][64 n]
  __shared__ float sx[2][256];                 // [buf][16 steps][16 p]
  __shared__ float sdtA[2][32];                // [buf][step*2 + {0:dt,1:dA}]
  __shared__ float part[16][16][20];           // [step][p][nq] (+pad)

  const float* dtp = dtt + (size_t)h * BL;
  const float* dap = dac + (size_t)h * BL;
  size_t gb = (size_t)b * LSEQ + t0;   // global row base of this chunk (B/C/dt/y)
  size_t cb = (size_t)b * CH;          // xhc chunk-local row base
  const int xcol = h * 64 + pq * 16;

  auto issueBCx = [&](int g, int nb) {
    size_t rbc = (gb + g * 16 + (tid >> 4)) * 64 + (tid & 15) * 4;
    load_lds16(Bc + rbc, &sB[nb][tid * 4]);    // dest = lane*16B linear: DMA constraint OK
    load_lds16(Cc + rbc, &sC[nb][tid * 4]);
    if (tid < 64)
      load_lds16(xhc + (cb + g * 16 + (tid >> 2)) * (size_t)D_INNER + xcol + (tid & 3) * 4,
                 &sx[nb][tid * 4]);
  };

  // prologue: group 0
  float dreg0 = 0.f;
  if (tid < 32) dreg0 = ((tid & 1) ? dap : dtp)[gb + (tid >> 1)];
  issueBCx(0, 0);
  if (tid < 32) sdtA[0][tid] = dreg0;
  __syncthreads();

  const int ngroups = CH / 16;
  for (int g = 0; g < ngroups; ++g) {
    int buf = g & 1, nbuf = buf ^ 1;
    float dreg = 0.f;
    bool pf = (g + 1 < ngroups);
    if (pf) {
      issueBCx(g + 1, nbuf);
      if (tid < 32) dreg = ((tid & 1) ? dap : dtp)[gb + (g + 1) * 16 + (tid >> 1)];
    }
#pragma unroll
    for (int j = 0; j < 16; ++j) {
      float2 dd = *(const float2*)&sdtA[buf][2 * j];   // x=dt, y=dA
      float xv = sx[buf][j * 16 + pl];
      float cf = dd.x * xv;
      float4 bv = *(const float4*)&sB[buf][j * 64 + n0];
      float4 cv = *(const float4*)&sC[buf][j * 64 + n0];
      s0 = dd.y * s0 + cf * bv.x;
      s1 = dd.y * s1 + cf * bv.y;
      s2 = dd.y * s2 + cf * bv.z;
      s3 = dd.y * s3 + cf * bv.w;
      part[j][pl][nq] = s0 * cv.x + s1 * cv.y + s2 * cv.z + s3 * cv.w;
    }
    if (pf && tid < 32) sdtA[nbuf][tid] = dreg;
    __syncthreads();   // partials visible; prefetched async loads also drained here
    {
      int jj = tid >> 4, pp = tid & 15;
      const float4* pr = (const float4*)&part[jj][pp][0];
      float4 a0 = pr[0], a1 = pr[1], a2 = pr[2], a3 = pr[3];
      float sum = (((a0.x + a0.y) + (a0.z + a0.w)) + ((a1.x + a1.y) + (a1.z + a1.w)))
                + (((a2.x + a2.y) + (a2.z + a2.w)) + ((a3.x + a3.y) + (a3.z + a3.w)));
      float xv2 = sx[buf][jj * 16 + pp];
      y[(gb + g * 16 + jj) * (size_t)D_INNER + h * 64 + pq * 16 + pp] = sum + Dh * xv2;
    }
    __syncthreads();   // part/buffers reusable
  }
  float4 sv = {s0, s1, s2, s3};
  *(float4*)&state[sidx] = sv;
}

// ---------------- gate (y * silu(z)) + RMSNorm * rms_w -> fp16 G, IN PLACE over Zb ----------
// G row r (2048 fp16) exactly overlays Zb row r (2048 fp16). All z reads happen into
// registers before the reduction barrier; writes only after it.
__global__ __launch_bounds__(256) void gate_rms_kernel(const float* __restrict__ yf,
                                                       const _Float16* __restrict__ zb,
                                                       const float* __restrict__ rw,
                                                       _Float16* __restrict__ g) {
  int row = blockIdx.x, tid = threadIdx.x;
  const float* yr = yf + (size_t)row * D_INNER;
  const _Float16* zr = zb + (size_t)row * D_INNER;
  float gv[8];
  float q = 0.f;
#pragma unroll
  for (int u = 0; u < 8; ++u) {
    int c = u * 256 + tid;
    float yv = yr[c];
    float zv = (float)zr[c];
    float t = yv * (zv / (1.f + __expf(-zv)));
    gv[u] = t;
    q += t * t;
  }
  for (int off = 1; off < 64; off <<= 1) q += __shfl_xor(q, off);
  __shared__ float rq[4];
  if ((tid & 63) == 0) rq[tid >> 6] = q;
  __syncthreads();    // all reads of this row are done before writes below
  q = rq[0] + rq[1] + rq[2] + rq[3];
  float scale = rsqrtf(q * (1.f / D_INNER) + EPS);
  _Float16* gr = g + (size_t)row * D_INNER;
#pragma unroll
  for (int u = 0; u < 8; ++u) {
    int c = u * 256 + tid;
    gr[c] = (_Float16)(gv[u] * scale * rw[c]);
  }
}

extern "C" void kernel_launch(void* const* d_in, const int* in_sizes, int n_in,
                              void* d_out, int out_size, void* d_ws, size_t ws_size,
                              hipStream_t stream) {
  (void)in_sizes; (void)n_in; (void)out_size; (void)ws_size;
  const float* x     = (const float*)d_in[0];
  const float* ln_w  = (const float*)d_in[1];
  const float* ln_b  = (const float*)d_in[2];
  const float* w_in  = (const float*)d_in[3];
  const float* cw    = (const float*)d_in[4];
  const float* cb    = (const float*)d_in[5];
  const float* dtb   = (const float*)d_in[6];
  const float* alog  = (const float*)d_in[7];
  const float* dvec  = (const float*)d_in[8];
  const float* rmsw  = (const float*)d_in[9];
  const float* w_out = (const float*)d_in[10];
  float* out = (float*)d_out;

  // Workspace budget: known-good high-water mark 253.8 MB (R2 crashed at 287 MB).
  // Total here ≈ 190 MB. REGION hosts LN fp16 (ln->gemm1) then Yf fp32 (scan->gate) —
  // non-overlapping lifetimes. G (gate output) overlays Zb in place. Layer-0 hidden
  // state H lives in d_out.
  char* ws = (char*)d_ws;
  size_t off = 0;
  auto alloc = [&](size_t bytes) -> char* {
    char* p = ws + off;
    off += (bytes + 255) & ~(size_t)255;
    return p;
  };
  _Float16* W1 = (_Float16*)alloc(2ull * 2 * NPAD1 * 1024);   // 17.8 MB
  _Float16* W2 = (_Float16*)alloc(2ull * 2 * 1024 * 2048);    //  8.4 MB
  char* REGION = alloc(4ull * BL * D_INNER);                  // 67.1 MB
  _Float16* LNf = (_Float16*)REGION;                          //  (16.8)
  float* Yf = (float*)REGION;                                 //  (67.1)
  _Float16* Zb = (_Float16*)alloc(2ull * BL * D_INNER);       // 33.6 MB
  _Float16* XPRE = (_Float16*)alloc(2ull * BL * D_INNER);     // 33.6 MB
  float* AUX  = (float*)alloc(4ull * BL * 160);               //  5.2 MB
  float* XHC  = (float*)alloc(4ull * 2 * CH * D_INNER);       // 16.8 MB
  float* BC = (float*)alloc(4ull * BL * D_STATE);             //  2.1 MB
  float* CC = (float*)alloc(4ull * BL * D_STATE);             //  2.1 MB
  float* DTt = (float*)alloc(4ull * NHEADS * BL);             //  1.0 MB
  float* DA  = (float*)alloc(4ull * NHEADS * BL);             //  1.0 MB
  float* STATE = (float*)alloc(4ull * 256 * 256 * 4);         //  1.0 MB

  cvt_w1_kernel<<<(2 * NPAD1 * 1024) / 256, 256, 0, stream>>>(w_in, W1);
  cvt_w2_kernel<<<(2 * 1024 * 2048) / 256, 256, 0, stream>>>(w_out, W2);

  for (int layer = 0; layer < 2; ++layer) {
    const float* hin = layer ? (const float*)out : x;
    size_t o1 = (size_t)layer * NPAD1 * 1024;
    size_t o2 = (size_t)layer * 1024 * 2048;
    ln_kernel<<<BL, 256, 0, stream>>>(hin, ln_w + layer * D_MODEL, ln_b + layer * D_MODEL, LNf);
    gemm_f16_kernel<0><<<dim3(NPAD1 / 128, BL / 128), 256, 0, stream>>>(
        LNf, 1024, W1 + o1, 1024, Zb, XPRE, AUX, nullptr, nullptr);
    dt_kernel<<<(NHEADS * BL) / 256, 256, 0, stream>>>(AUX, dtb + layer * NHEADS,
                                                       alog + layer * NHEADS, DTt, DA);
    for (int k = 0; k < LSEQ / CH; ++k) {
      conv_chunk_kernel<<<dim3(2 * CH, 9), 256, 0, stream>>>(
          XPRE, AUX, cw + layer * CONV_DIM * 4, cb + layer * CONV_DIM, k * CH, XHC, BC, CC);
      scan_chunk_kernel<<<256, 256, 0, stream>>>(
          XHC, BC, CC, DTt, DA, dvec + layer * NHEADS, k * CH, STATE, Yf);
    }
    // gate + RMSNorm: reads Yf + Zb(z), writes G fp16 in place over Zb
    gate_rms_kernel<<<BL, 256, 0, stream>>>(Yf, Zb, rmsw + layer * D_INNER, Zb);
    gemm_f16_kernel<1><<<dim3(1024 / 128, BL / 128), 256, 0, stream>>>(
        Zb, 2048, W2 + o2, 2048, nullptr, nullptr, nullptr, out, hin);
  }
}

// Round 7
// 1318.629 us; speedup vs baseline: 2.7737x; 1.0580x over previous
//
#include <hip/hip_runtime.h>
#include <stdint.h>

#define D_MODEL   1024
#define D_STATE   64
#define D_INNER   2048
#define NHEADS    32
#define CONV_DIM  2176
#define D_IN_PROJ 4256
#define NPAD1     4352   // 34*128, padded N for in_proj GEMM
#define LSEQ      4096
#define BL        8192   // B*L
#define NCHUNK    32     // scan time-chunks
#define TCH       128    // steps per chunk
#define EPS       1e-5f

typedef __attribute__((ext_vector_type(8))) _Float16 f16x8;
typedef __attribute__((ext_vector_type(4))) _Float16 f16x4;
typedef __attribute__((ext_vector_type(4))) float f32x4;

__device__ __forceinline__ void load_lds16(const void* g, void* l) {
  __builtin_amdgcn_global_load_lds((const __attribute__((address_space(1))) void*)g,
                                   (__attribute__((address_space(3))) void*)l, 16, 0, 0);
}

// ---------------- weight casts: fp32 -> fp16 ----------------
__global__ __launch_bounds__(256) void cvt_w1_kernel(const float* __restrict__ w,
                                                     _Float16* __restrict__ o) {
  size_t idx = (size_t)blockIdx.x * 256 + threadIdx.x;   // over 2*4352*1024
  int k = idx & 1023;
  size_t nr = idx >> 10;
  int layer = (int)(nr / NPAD1);
  int n = (int)(nr % NPAD1);
  float v = (n < D_IN_PROJ) ? w[((size_t)layer * D_IN_PROJ + n) * 1024 + k] : 0.f;
  o[idx] = (_Float16)v;
}
__global__ __launch_bounds__(256) void cvt_w2_kernel(const float* __restrict__ w,
                                                     _Float16* __restrict__ o) {
  size_t idx = (size_t)blockIdx.x * 256 + threadIdx.x;   // over 2*1024*2048
  o[idx] = (_Float16)w[idx];
}

// ---------------- layernorm (row of 1024), fp32 in -> fp16 out ----------------
__global__ __launch_bounds__(256) void ln_kernel(const float* __restrict__ x,
                                                 const float* __restrict__ w,
                                                 const float* __restrict__ b,
                                                 _Float16* __restrict__ o) {
  int row = blockIdx.x, tid = threadIdx.x;
  const float* xr = x + (size_t)row * D_MODEL;
  float4 v = *(const float4*)(xr + tid * 4);
  float s = v.x + v.y + v.z + v.w;
  float q = v.x * v.x + v.y * v.y + v.z * v.z + v.w * v.w;
  for (int off = 1; off < 64; off <<= 1) { s += __shfl_xor(s, off); q += __shfl_xor(q, off); }
  __shared__ float rs[4], rq[4];
  int wave = tid >> 6, lane = tid & 63;
  if (lane == 0) { rs[wave] = s; rq[wave] = q; }
  __syncthreads();
  s = rs[0] + rs[1] + rs[2] + rs[3];
  q = rq[0] + rq[1] + rq[2] + rq[3];
  float mean = s * (1.f / D_MODEL);
  float var = q * (1.f / D_MODEL) - mean * mean;
  float rstd = rsqrtf(var + EPS);
  int c = tid * 4;
  f16x4 ov;
  ov[0] = (_Float16)((v.x - mean) * rstd * w[c + 0] + b[c + 0]);
  ov[1] = (_Float16)((v.y - mean) * rstd * w[c + 1] + b[c + 1]);
  ov[2] = (_Float16)((v.z - mean) * rstd * w[c + 2] + b[c + 2]);
  ov[3] = (_Float16)((v.w - mean) * rstd * w[c + 3] + b[c + 3]);
  *(f16x4*)(o + (size_t)row * D_MODEL + c) = ov;
}

// ---------------- fp16 GEMM, C[m,n] = sum_k A[m,k]*B[n,k]  (m97 structure) ----------------
template <int MODE>
__global__ __launch_bounds__(256) void gemm_f16_kernel(
    const _Float16* __restrict__ A, int lda,
    const _Float16* __restrict__ Bw, int K,
    _Float16* __restrict__ Zb, _Float16* __restrict__ XPRE, float* __restrict__ AUX,
    float* __restrict__ Cf, const float* __restrict__ resid) {
  __shared__ _Float16 lA[128 * 32];
  __shared__ _Float16 lB[128 * 32];
  int tid = threadIdx.x;
  int wave = tid >> 6, lane = tid & 63;
  int bn = blockIdx.x, bm = blockIdx.y;
  const int rA = lane >> 2;
  const int cA = (lane & 3) * 8;     // 16B per lane; DMA lane-linear dest
  const int wm = (wave >> 1) * 64, wn = (wave & 1) * 64;
  const int fr = lane & 15;
  const int fk = (lane >> 4) * 8;
  size_t aoff = (size_t)(bm * 128) * lda;
  size_t boff = (size_t)(bn * 128) * K;
  f32x4 acc[4][4];
  f32x4 zero = {0.f, 0.f, 0.f, 0.f};
#pragma unroll
  for (int i = 0; i < 4; ++i)
#pragma unroll
    for (int j = 0; j < 4; ++j) acc[i][j] = zero;

  for (int k0 = 0; k0 < K; k0 += 32) {
#pragma unroll
    for (int c = 0; c < 2; ++c) {
      int row = (wave * 2 + c) * 16 + rA;
      load_lds16(A + aoff + (size_t)row * lda + k0 + cA, &lA[row * 32 + cA]);
      load_lds16(Bw + boff + (size_t)row * K + k0 + cA, &lB[row * 32 + cA]);
    }
    __syncthreads();
    f16x8 af[4], bf[4];
#pragma unroll
    for (int i = 0; i < 4; ++i) af[i] = *(const f16x8*)&lA[(wm + i * 16 + fr) * 32 + fk];
#pragma unroll
    for (int j = 0; j < 4; ++j) bf[j] = *(const f16x8*)&lB[(wn + j * 16 + fr) * 32 + fk];
#pragma unroll
    for (int i = 0; i < 4; ++i)
#pragma unroll
      for (int j = 0; j < 4; ++j)
        acc[i][j] = __builtin_amdgcn_mfma_f32_16x16x32_f16(af[i], bf[j], acc[i][j], 0, 0, 0);
    __syncthreads();
  }
  int r0 = (lane >> 4) * 4;
  int cc = lane & 15;
#pragma unroll
  for (int i = 0; i < 4; ++i) {
#pragma unroll
    for (int j = 0; j < 4; ++j) {
      int col = bn * 128 + wn + j * 16 + cc;
#pragma unroll
      for (int r = 0; r < 4; ++r) {
        size_t row = (size_t)(bm * 128 + wm + i * 16 + r0 + r);
        float v = acc[i][j][r];
        if constexpr (MODE == 0) {
          if (col < 2048)       Zb[row * 2048 + col] = (_Float16)v;
          else if (col < 4096)  XPRE[row * 2048 + (col - 2048)] = (_Float16)v;
          else if (col < 4256)  AUX[row * 160 + (col - 4096)] = v;
        } else {
          size_t idx = row * 1024 + col;
          Cf[idx] = v + resid[idx];
        }
      }
    }
  }
}

// ---------------- dt = softplus(dt_raw + dt_bias) + dA = exp(dt*A), transposed [h][l] -------
__global__ __launch_bounds__(256) void dt_kernel(const float* __restrict__ aux,
                                                 const float* __restrict__ dtb,
                                                 const float* __restrict__ alog,
                                                 float* __restrict__ dtt,
                                                 float* __restrict__ da) {
  int idx = blockIdx.x * 256 + threadIdx.x;   // over 32*8192, h-major
  int h = idx >> 13, l = idx & 8191;
  float A = -__expf(alog[h]);                 // A = -exp(A_log); __expf IS e^x
  float v = aux[(size_t)l * 160 + 128 + h] + dtb[h];
  float sp = (v > 20.f) ? v : log1pf(expf(v));
  dtt[idx] = sp;
  da[idx] = __expf(sp * A);
}

// ---------------- within-chunk cumulative decay: cumda[t] = prod_{chunk start..t} dA ------
__global__ __launch_bounds__(256) void cumda_kernel(const float* __restrict__ da,
                                                    float* __restrict__ cumda) {
  int idx = blockIdx.x * 256 + threadIdx.x;   // < 32*2*32 = 2048 (h,b,chunk)
  int h = idx >> 6, b = (idx >> 5) & 1, ct = idx & 31;
  size_t base = (size_t)h * BL + b * LSEQ + ct * TCH;
  float cum = 1.f;
  for (int t = 0; t < TCH; ++t) { cum *= da[base + t]; cumda[base + t] = cum; }
}

// ---------------- causal depthwise conv (width 4) + bias + silu, full length ----------------
__global__ __launch_bounds__(256) void conv_kernel(const _Float16* __restrict__ xpre,
                                                   const float* __restrict__ aux,
                                                   const float* __restrict__ cw,
                                                   const float* __restrict__ cb,
                                                   _Float16* __restrict__ xh,
                                                   float* __restrict__ Bo,
                                                   float* __restrict__ Co) {
  int l = blockIdx.x;                       // 0..8191
  int c = blockIdx.y * 256 + threadIdx.x;
  if (c >= CONV_DIM) return;
  int t = l & 4095;
  float acc = cb[c];
#pragma unroll
  for (int j = 0; j < 4; ++j) {
    int tt = t - 3 + j;
    if (tt >= 0) {
      size_t ll = (size_t)(l - 3 + j);
      float xv = (c < 2048) ? (float)xpre[ll * 2048 + c] : aux[ll * 160 + (c - 2048)];
      acc += xv * cw[c * 4 + j];
    }
  }
  acc = acc / (1.f + __expf(-acc));   // silu
  if (c < D_INNER)
    xh[(size_t)l * D_INNER + c] = (_Float16)acc;
  else if (c < D_INNER + D_STATE)
    Bo[(size_t)l * D_STATE + (c - D_INNER)] = acc;
  else
    Co[(size_t)l * D_STATE + (c - D_INNER - D_STATE)] = acc;
}

// ---------------- scan pass 1: per-chunk local scan from zero state ----------------
// grid 8192: bid = (b,h,pq,chunk). Thread: pl=tid>>4 (p row), nq=tid&15 (n quad).
// Writes partial y (no cross-chunk term), end-state to CS.
__global__ __launch_bounds__(256) void scan_p1_kernel(const _Float16* __restrict__ xh,
                                                      const float* __restrict__ Bc,
                                                      const float* __restrict__ Cc,
                                                      const float* __restrict__ dtt,
                                                      const float* __restrict__ dac,
                                                      const float* __restrict__ Dv,
                                                      float* __restrict__ cs,
                                                      float* __restrict__ y) {
  int bid = blockIdx.x;
  int chunk = bid & 31, pq = (bid >> 5) & 3, h = (bid >> 7) & 31, b = bid >> 12;
  int tid = threadIdx.x;
  int pl = tid >> 4;
  int nq = tid & 15;
  int n0 = nq * 4;
  float Dh = Dv[h];
  float s0 = 0.f, s1 = 0.f, s2 = 0.f, s3 = 0.f;

  __shared__ float sB[2][1024], sC[2][1024];   // [buf][16 steps][64 n]
  __shared__ _Float16 sx16[2][256];            // [buf][16 steps][16 p]
  __shared__ float sdtA[2][32];                // [buf][step*2 + {0:dt,1:dA}]
  __shared__ float part[16][16][20];           // [step][p][nq] (+pad)

  const float* dtp = dtt + (size_t)h * BL;
  const float* dap = dac + (size_t)h * BL;
  size_t gb = (size_t)b * LSEQ + chunk * TCH;
  const int xcol = h * 64 + pq * 16;

  auto issue = [&](int g, int nb) {
    size_t rbc = (gb + g * 16 + (tid >> 4)) * 64 + (tid & 15) * 4;
    load_lds16(Bc + rbc, &sB[nb][tid * 4]);    // dest lane-linear 16B: DMA constraint OK
    load_lds16(Cc + rbc, &sC[nb][tid * 4]);
    if (tid < 32)
      load_lds16(xh + (gb + g * 16 + (tid >> 1)) * (size_t)D_INNER + xcol + (tid & 1) * 8,
                 &sx16[nb][tid * 8]);
  };

  float dreg0 = 0.f;
  if (tid < 32) dreg0 = ((tid & 1) ? dap : dtp)[gb + (tid >> 1)];
  issue(0, 0);
  if (tid < 32) sdtA[0][tid] = dreg0;
  __syncthreads();

  const int ngroups = TCH / 16;
  for (int g = 0; g < ngroups; ++g) {
    int buf = g & 1, nbuf = buf ^ 1;
    float dreg = 0.f;
    bool pf = (g + 1 < ngroups);
    if (pf) {
      issue(g + 1, nbuf);
      if (tid < 32) dreg = ((tid & 1) ? dap : dtp)[gb + (g + 1) * 16 + (tid >> 1)];
    }
#pragma unroll
    for (int j = 0; j < 16; ++j) {
      float2 dd = *(const float2*)&sdtA[buf][2 * j];   // x=dt, y=dA
      float xv = (float)sx16[buf][j * 16 + pl];
      float cf = dd.x * xv;
      float4 bv = *(const float4*)&sB[buf][j * 64 + n0];
      float4 cv = *(const float4*)&sC[buf][j * 64 + n0];
      s0 = dd.y * s0 + cf * bv.x;
      s1 = dd.y * s1 + cf * bv.y;
      s2 = dd.y * s2 + cf * bv.z;
      s3 = dd.y * s3 + cf * bv.w;
      part[j][pl][nq] = s0 * cv.x + s1 * cv.y + s2 * cv.z + s3 * cv.w;
    }
    if (pf && tid < 32) sdtA[nbuf][tid] = dreg;
    __syncthreads();
    {
      int jj = tid >> 4, pp = tid & 15;
      const float4* pr = (const float4*)&part[jj][pp][0];
      float4 a0 = pr[0], a1 = pr[1], a2 = pr[2], a3 = pr[3];
      float sum = (((a0.x + a0.y) + (a0.z + a0.w)) + ((a1.x + a1.y) + (a1.z + a1.w)))
                + (((a2.x + a2.y) + (a2.z + a2.w)) + ((a3.x + a3.y) + (a3.z + a3.w)));
      float xv2 = (float)sx16[buf][jj * 16 + pp];
      y[(gb + g * 16 + jj) * (size_t)D_INNER + h * 64 + pq * 16 + pp] = sum + Dh * xv2;
    }
    __syncthreads();
  }
  size_t cslot = (((size_t)(b * 32 + h) * 32 + chunk) * 4096) + (size_t)(pq * 256 + tid) * 4;
  float4 sv = {s0, s1, s2, s3};
  *(float4*)&cs[cslot] = sv;
}

// ---------------- scan pass 2: prefix over chunks, IN PLACE (E_c -> S_{c-1}) ----------------
__global__ __launch_bounds__(256) void scan_p2_kernel(float* __restrict__ cs,
                                                      const float* __restrict__ cumda) {
  int bid = blockIdx.x;    // (b,h,pq)
  int b = bid >> 7, h = (bid >> 2) & 31, pq = bid & 3;
  int tid = threadIdx.x;
  size_t base = ((size_t)(b * 32 + h) * 32) * 4096 + (size_t)(pq * 256 + tid) * 4;
  const float* cd = cumda + (size_t)h * BL + b * LSEQ;
  float4 s = {0.f, 0.f, 0.f, 0.f};
  for (int c = 0; c < NCHUNK; ++c) {
    size_t idx = base + (size_t)c * 4096;
    float4 e = *(const float4*)&cs[idx];
    float P = cd[c * TCH + TCH - 1];      // total decay of chunk c
    *(float4*)&cs[idx] = s;               // prefix state entering chunk c
    s.x = e.x + P * s.x;
    s.y = e.y + P * s.y;
    s.z = e.z + P * s.z;
    s.w = e.w + P * s.w;
  }
}

// ---------------- scan pass 3: y[t] += cumda(t) * (C_t . S_prev) ----------------
__global__ __launch_bounds__(256) void scan_p3_kernel(const float* __restrict__ cs,
                                                      const float* __restrict__ Cc,
                                                      const float* __restrict__ cumda,
                                                      float* __restrict__ y) {
  int bid = blockIdx.x;
  int chunk = bid & 31, pq = (bid >> 5) & 3, h = (bid >> 7) & 31, b = bid >> 12;
  int tid = threadIdx.x;
  int pl = tid >> 4;
  int nq = tid & 15;
  int n0 = nq * 4;
  size_t cslot = (((size_t)(b * 32 + h) * 32 + chunk) * 4096) + (size_t)(pq * 256 + tid) * 4;
  float4 sp = *(const float4*)&cs[cslot];

  __shared__ float sC[2][1024];
  __shared__ float scd[2][16];
  __shared__ float part[16][16][20];

  size_t gb = (size_t)b * LSEQ + chunk * TCH;
  size_t cdb = (size_t)h * BL + b * LSEQ + chunk * TCH;

  auto issue = [&](int g, int nb) {
    size_t rbc = (gb + g * 16 + (tid >> 4)) * 64 + (tid & 15) * 4;
    load_lds16(Cc + rbc, &sC[nb][tid * 4]);
    if (tid < 4) load_lds16(cumda + cdb + g * 16 + tid * 4, &scd[nb][tid * 4]);
  };

  issue(0, 0);
  __syncthreads();
  const int ngroups = TCH / 16;
  for (int g = 0; g < ngroups; ++g) {
    int buf = g & 1, nbuf = buf ^ 1;
    if (g + 1 < ngroups) issue(g + 1, nbuf);
#pragma unroll
    for (int j = 0; j < 16; ++j) {
      float4 cv = *(const float4*)&sC[buf][j * 64 + n0];
      part[j][pl][nq] = sp.x * cv.x + sp.y * cv.y + sp.z * cv.z + sp.w * cv.w;
    }
    __syncthreads();
    {
      int jj = tid >> 4, pp = tid & 15;
      const float4* pr = (const float4*)&part[jj][pp][0];
      float4 a0 = pr[0], a1 = pr[1], a2 = pr[2], a3 = pr[3];
      float sum = (((a0.x + a0.y) + (a0.z + a0.w)) + ((a1.x + a1.y) + (a1.z + a1.w)))
                + (((a2.x + a2.y) + (a2.z + a2.w)) + ((a3.x + a3.y) + (a3.z + a3.w)));
      size_t idx = (gb + g * 16 + jj) * (size_t)D_INNER + h * 64 + pq * 16 + pp;
      y[idx] += scd[buf][jj] * sum;
    }
    __syncthreads();
  }
}

// ---------------- gate (y * silu(z)) + RMSNorm * rms_w -> fp16 G, IN PLACE over Zb ----------
__global__ __launch_bounds__(256) void gate_rms_kernel(const float* __restrict__ yf,
                                                       const _Float16* __restrict__ zb,
                                                       const float* __restrict__ rw,
                                                       _Float16* __restrict__ g) {
  int row = blockIdx.x, tid = threadIdx.x;
  const float* yr = yf + (size_t)row * D_INNER;
  const _Float16* zr = zb + (size_t)row * D_INNER;
  float gv[8];
  float q = 0.f;
#pragma unroll
  for (int u = 0; u < 8; ++u) {
    int c = u * 256 + tid;
    float yv = yr[c];
    float zv = (float)zr[c];
    float t = yv * (zv / (1.f + __expf(-zv)));
    gv[u] = t;
    q += t * t;
  }
  for (int off = 1; off < 64; off <<= 1) q += __shfl_xor(q, off);
  __shared__ float rq[4];
  if ((tid & 63) == 0) rq[tid >> 6] = q;
  __syncthreads();    // all reads of this row are done before writes below
  q = rq[0] + rq[1] + rq[2] + rq[3];
  float scale = rsqrtf(q * (1.f / D_INNER) + EPS);
  _Float16* gr = g + (size_t)row * D_INNER;
#pragma unroll
  for (int u = 0; u < 8; ++u) {
    int c = u * 256 + tid;
    gr[c] = (_Float16)(gv[u] * scale * rw[c]);
  }
}

extern "C" void kernel_launch(void* const* d_in, const int* in_sizes, int n_in,
                              void* d_out, int out_size, void* d_ws, size_t ws_size,
                              hipStream_t stream) {
  (void)in_sizes; (void)n_in; (void)out_size; (void)ws_size;
  const float* x     = (const float*)d_in[0];
  const float* ln_w  = (const float*)d_in[1];
  const float* ln_b  = (const float*)d_in[2];
  const float* w_in  = (const float*)d_in[3];
  const float* cw    = (const float*)d_in[4];
  const float* cb    = (const float*)d_in[5];
  const float* dtb   = (const float*)d_in[6];
  const float* alog  = (const float*)d_in[7];
  const float* dvec  = (const float*)d_in[8];
  const float* rmsw  = (const float*)d_in[9];
  const float* w_out = (const float*)d_in[10];
  float* out = (float*)d_out;

  // Workspace budget: known-good high-water mark 253.8 MB (R2 crashed at 287 MB).
  // Total here ≈ 240 MB. REGION hosts LN fp16 (ln->gemm1) then Yf fp32 (scan->gate).
  // G overlays Zb in place. Layer-0 hidden state H lives in d_out.
  char* ws = (char*)d_ws;
  size_t off = 0;
  auto alloc = [&](size_t bytes) -> char* {
    char* p = ws + off;
    off += (bytes + 255) & ~(size_t)255;
    return p;
  };
  _Float16* W1 = (_Float16*)alloc(2ull * 2 * NPAD1 * 1024);   // 17.8 MB
  _Float16* W2 = (_Float16*)alloc(2ull * 2 * 1024 * 2048);    //  8.4 MB
  char* REGION = alloc(4ull * BL * D_INNER);                  // 67.1 MB
  _Float16* LNf = (_Float16*)REGION;                          //  (16.8)
  float* Yf = (float*)REGION;                                 //  (67.1)
  _Float16* Zb = (_Float16*)alloc(2ull * BL * D_INNER);       // 33.6 MB
  _Float16* XPRE = (_Float16*)alloc(2ull * BL * D_INNER);     // 33.6 MB
  _Float16* XH = (_Float16*)alloc(2ull * BL * D_INNER);       // 33.6 MB
  float* AUX  = (float*)alloc(4ull * BL * 160);               //  5.2 MB
  float* BC = (float*)alloc(4ull * BL * D_STATE);             //  2.1 MB
  float* CC = (float*)alloc(4ull * BL * D_STATE);             //  2.1 MB
  float* DTt = (float*)alloc(4ull * NHEADS * BL);             //  1.0 MB
  float* DA  = (float*)alloc(4ull * NHEADS * BL);             //  1.0 MB
  float* CUMDA = (float*)alloc(4ull * NHEADS * BL);           //  1.0 MB
  float* CS = (float*)alloc(4ull * 2 * NHEADS * NCHUNK * 4096); // 33.6 MB

  cvt_w1_kernel<<<(2 * NPAD1 * 1024) / 256, 256, 0, stream>>>(w_in, W1);
  cvt_w2_kernel<<<(2 * 1024 * 2048) / 256, 256, 0, stream>>>(w_out, W2);

  for (int layer = 0; layer < 2; ++layer) {
    const float* hin = layer ? (const float*)out : x;
    size_t o1 = (size_t)layer * NPAD1 * 1024;
    size_t o2 = (size_t)layer * 1024 * 2048;
    ln_kernel<<<BL, 256, 0, stream>>>(hin, ln_w + layer * D_MODEL, ln_b + layer * D_MODEL, LNf);
    gemm_f16_kernel<0><<<dim3(NPAD1 / 128, BL / 128), 256, 0, stream>>>(
        LNf, 1024, W1 + o1, 1024, Zb, XPRE, AUX, nullptr, nullptr);
    dt_kernel<<<(NHEADS * BL) / 256, 256, 0, stream>>>(AUX, dtb + layer * NHEADS,
                                                       alog + layer * NHEADS, DTt, DA);
    cumda_kernel<<<8, 256, 0, stream>>>(DA, CUMDA);
    conv_kernel<<<dim3(BL, 9), 256, 0, stream>>>(XPRE, AUX, cw + layer * CONV_DIM * 4,
                                                 cb + layer * CONV_DIM, XH, BC, CC);
    scan_p1_kernel<<<8192, 256, 0, stream>>>(XH, BC, CC, DTt, DA, dvec + layer * NHEADS,
                                             CS, Yf);
    scan_p2_kernel<<<256, 256, 0, stream>>>(CS, CUMDA);
    scan_p3_kernel<<<8192, 256, 0, stream>>>(CS, CC, CUMDA, Yf);
    gate_rms_kernel<<<BL, 256, 0, stream>>>(Yf, Zb, rmsw + layer * D_INNER, Zb);
    gemm_f16_kernel<1><<<dim3(1024 / 128, BL / 128), 256, 0, stream>>>(
        Zb, 2048, W2 + o2, 2048, nullptr, nullptr, nullptr, out, hin);
  }
}